// Round 14
// baseline (233.983 us; speedup 1.0000x reference)
//
#include <hip/hip_runtime.h>

#define TPB 256
#define NSCAT 512         // scatter blocks inside the fused kernel (R13-proven)
#define BSH 5             // node >> 5 -> bucket; 32 dsts per bucket
#define BCAP 1024         // fixed packed-region size per bucket (mean 512, +22sigma)
#define MAXBUK 3200       // LDS sizing cap for bucket arrays (N <= 102400)

typedef __attribute__((ext_vector_type(4))) float f32x4;
typedef __attribute__((ext_vector_type(8))) short short8;

__device__ __forceinline__ unsigned short f2bf(float f) {
    unsigned u = __float_as_uint(f);
    u = (u + 0x7fffu + ((u >> 16) & 1u)) >> 16;
    return (unsigned short)u;
}
__device__ __forceinline__ float bflo(unsigned u) { return __uint_as_float(u << 16); }
__device__ __forceinline__ float bfhi(unsigned u) { return __uint_as_float(u & 0xffff0000u); }

// ============ pass 1 (fused): bucket scatter (blocks 0..NSCAT-1) || gemm ========
// R13-proven, unchanged. Scatter: LDS hist -> cursor conversion (one returning
// base-grab per (block,bucket)) -> LDS-cursor scatter into fixed regions.
// Gemm: unscaled g = x@W^T via MFMA, W staged in two 64-row half-tiles.

__global__ __launch_bounds__(256) void k_scatgemm(
    const int* __restrict__ src, const int* __restrict__ dst,
    int* __restrict__ bcur, unsigned* __restrict__ packed,
    const float* __restrict__ x, const float* __restrict__ W,
    unsigned short* __restrict__ g, int N, int E, int NBUK)
{
    __shared__ __align__(16) char smem[17408];
    const int t = threadIdx.x;

    if (blockIdx.x < NSCAT) {
        // ---------------- scatter half ----------------
        int* a = (int*)smem;                       // NBUK ints = 12.5 KB
        for (int i = t; i < NBUK; i += 256) a[i] = 0;
        __syncthreads();
        const int chunk = (E + NSCAT - 1) / NSCAT;
        const int lo = blockIdx.x * chunk;
        const int hi = min(E, lo + chunk);
        for (int e = lo + t; e < hi; e += 256)
            atomicAdd(&a[dst[e] >> BSH], 1);       // LDS atomic (hist)
        __syncthreads();
        for (int i = t; i < NBUK; i += 256) {
            int c = a[i];                          // count -> absolute cursor
            a[i] = i * BCAP + (c ? atomicAdd(&bcur[i], c) : 0);  // base grab
        }
        __syncthreads();
        for (int e = lo + t; e < hi; e += 256) {
            int d = dst[e];
            int bkt = d >> BSH;
            int pos = atomicAdd(&a[bkt], 1);       // LDS atomic
            if (pos < bkt * BCAP + BCAP)           // overflow guard (never here)
                packed[pos] = ((unsigned)src[e] << 8) | (unsigned)(d & 31);
        }
    } else {
        // ---------------- gemm half: 2x 64-row W half-tiles ----------------
        typedef unsigned short wb_t[136];
        wb_t* wb = (wb_t*)smem;                    // [64][136] bf16 = 17408 B

        const int lane = t & 63;
        const int wid  = t >> 6;
        const int l15  = lane & 15;
        const int quad = lane >> 4;
        const int row  = (blockIdx.x - NSCAT) * 64 + wid * 16 + l15;
        const int rowc = (row < N) ? row : (N - 1);

        short8 af[4];
        #pragma unroll
        for (int ks = 0; ks < 4; ++ks) {
            const int kb = ks * 32 + quad * 8;
            float4 a0 = *(const float4*)(x + (long)rowc * 128 + kb);
            float4 a1 = *(const float4*)(x + (long)rowc * 128 + kb + 4);
            union { unsigned short u[8]; short8 v; } cf;
            cf.u[0] = f2bf(a0.x); cf.u[1] = f2bf(a0.y); cf.u[2] = f2bf(a0.z); cf.u[3] = f2bf(a0.w);
            cf.u[4] = f2bf(a1.x); cf.u[5] = f2bf(a1.y); cf.u[6] = f2bf(a1.z); cf.u[7] = f2bf(a1.w);
            af[ks] = cf.v;
        }

        f32x4 acc[8];
        #pragma unroll
        for (int u = 0; u < 8; ++u) acc[u] = (f32x4){0.f, 0.f, 0.f, 0.f};

        #pragma unroll
        for (int half = 0; half < 2; ++half) {
            for (int ch = t; ch < 1024; ch += 256) {       // stage 64 W rows
                int nrow = ch >> 4, k8 = (ch & 15) << 3;
                const float* wp = W + (half * 64 + nrow) * 128 + k8;
                float4 w0 = *(const float4*)wp;
                float4 w1 = *(const float4*)(wp + 4);
                union { unsigned short u[8]; uint4 q; } pk;
                pk.u[0] = f2bf(w0.x); pk.u[1] = f2bf(w0.y); pk.u[2] = f2bf(w0.z); pk.u[3] = f2bf(w0.w);
                pk.u[4] = f2bf(w1.x); pk.u[5] = f2bf(w1.y); pk.u[6] = f2bf(w1.z); pk.u[7] = f2bf(w1.w);
                *(uint4*)&wb[nrow][k8] = pk.q;
            }
            __syncthreads();
            #pragma unroll
            for (int ks = 0; ks < 4; ++ks) {
                const int kb = ks * 32 + quad * 8;
                #pragma unroll
                for (int u = 0; u < 4; ++u) {
                    short8 bf = *(const short8*)&wb[u * 16 + l15][kb];
                    // swapped: W frag as A, x frag as B  ->  D[j][i]
                    acc[half * 4 + u] =
                        __builtin_amdgcn_mfma_f32_16x16x32_bf16(bf, af[ks], acc[half * 4 + u], 0, 0, 0);
                }
            }
            __syncthreads();                       // before next half overwrites wb
        }

        if (row < N) {
            unsigned short* gp = g + (long)row * 128 + quad * 4;
            #pragma unroll
            for (int u = 0; u < 8; ++u) {
                unsigned short u0 = f2bf(acc[u][0]);
                unsigned short u1 = f2bf(acc[u][1]);
                unsigned short u2 = f2bf(acc[u][2]);
                unsigned short u3 = f2bf(acc[u][3]);
                uint2 pk;
                pk.x = (unsigned)u0 | ((unsigned)u1 << 16);
                pk.y = (unsigned)u2 | ((unsigned)u3 << 16);
                *(uint2*)(gp + u * 16) = pk;       // 4 consecutive bf16 cols
            }
        }
    }
}

// ============ pass 2: per-bucket degree -> dinv (tiny) ============

__global__ __launch_bounds__(256) void k_dinv(const unsigned* __restrict__ packed,
                                              const int* __restrict__ bcur,
                                              float* __restrict__ dinv, int N) {
    __shared__ int hist[32];
    const int b = blockIdx.x;
    const int t = threadIdx.x;
    if (t < 32) hist[t] = 0;
    __syncthreads();
    const int cnt = min(bcur[b], BCAP);
    const int base = b * BCAP;
    for (int e = t; e < cnt; e += 256)
        atomicAdd(&hist[packed[base + e] & 31u], 1);   // LDS atomic
    __syncthreads();
    if (t < 32) {
        int d = (b << BSH) + t;
        if (d < N) dinv[d] = rsqrtf((float)hist[t] + 1.0f);
    }
}

// ============ pass 3: fused LDS sort + aggregate, one 32-dst bucket per block ====
// R14 change: gather uses 16 lanes x uint4 (16B) per row — one wave-level load
// instruction now covers FOUR rows (1 KB) vs two (512B) with 32xuint2: half the
// load-issue slots, 2x bytes in flight per slot, same VALU and same coalescing.
// (R2's 16-lane failure was confounded by a 16-deep unroll pushing VGPR to 52;
// here the 8/4/1 ladder keeps VGPR ~40.) Bias hoisted out of the round loop.

__global__ __launch_bounds__(256) void k_aggsort(const unsigned* __restrict__ packed,
                                                 const int* __restrict__ bcur,
                                                 const float* __restrict__ dinv,
                                                 const unsigned short* __restrict__ g,
                                                 const float* __restrict__ b_,
                                                 float* __restrict__ out, int N) {
    __shared__ int hist[32], lbase[32], scur[32];
    __shared__ unsigned stage[BCAP];
    const int b = blockIdx.x;
    const int t = threadIdx.x;
    if (t < 32) hist[t] = 0;
    __syncthreads();
    const int cnt = min(bcur[b], BCAP);
    const int base = b * BCAP;
    for (int e = t; e < cnt; e += 256)
        atomicAdd(&hist[packed[base + e] & 31u], 1);   // LDS atomic
    __syncthreads();
    if (t < 32) {                                      // lanes 0..31 of wave 0
        int v = hist[t];
        int incl = v;
        #pragma unroll
        for (int d = 1; d < 32; d <<= 1) {
            int o = __shfl_up(incl, d);
            if (t >= d) incl += o;
        }
        lbase[t] = incl - v;
        scur[t]  = incl - v;
    }
    __syncthreads();
    for (int e = t; e < cnt; e += 256) {
        unsigned pk = packed[base + e];
        int pos = atomicAdd(&scur[pk & 31u], 1);       // LDS atomic
        stage[pos] = pk & 0xffffff00u;                 // byte offset (src*256)
    }
    __syncthreads();

    // aggregate: 16 dsts per round (16 lanes x 16B each), 2 rounds
    const int c = (t & 15) << 3;                       // 8 float columns per lane
    const char* gb = (const char*)g + (c << 1);        // 16B lane base in a g-row
    float4 b0 = *(const float4*)(b_ + c);              // bias hoisted (round-invariant)
    float4 b1 = *(const float4*)(b_ + c + 4);
    #pragma unroll 1
    for (int round = 0; round < 2; ++round) {
        const int dl = round * 16 + (t >> 4);
        const int d  = (b << BSH) + dl;
        if (d >= N) continue;

        float acc[8];
        #pragma unroll
        for (int j = 0; j < 8; ++j) acc[j] = 0.f;
        auto addrow = [&](unsigned off) {              // off = byte offset of g-row
            float dv = dinv[off >> 8];
            uint4 p = *(const uint4*)(gb + off);
            acc[0] = fmaf(bflo(p.x), dv, acc[0]);
            acc[1] = fmaf(bfhi(p.x), dv, acc[1]);
            acc[2] = fmaf(bflo(p.y), dv, acc[2]);
            acc[3] = fmaf(bfhi(p.y), dv, acc[3]);
            acc[4] = fmaf(bflo(p.z), dv, acc[4]);
            acc[5] = fmaf(bfhi(p.z), dv, acc[5]);
            acc[6] = fmaf(bflo(p.w), dv, acc[6]);
            acc[7] = fmaf(bfhi(p.w), dv, acc[7]);
        };

        addrow((unsigned)d << 8);                      // self-loop: dinv[d]*g[d]
        int e  = lbase[dl];
        int s1 = e + hist[dl];
        for (; e + 8 <= s1; e += 8) {
            unsigned a[8];
            #pragma unroll
            for (int j = 0; j < 8; ++j) a[j] = stage[e + j];
            #pragma unroll
            for (int j = 0; j < 8; ++j) addrow(a[j]);
        }
        for (; e + 4 <= s1; e += 4) {
            unsigned a[4];
            #pragma unroll
            for (int j = 0; j < 4; ++j) a[j] = stage[e + j];
            #pragma unroll
            for (int j = 0; j < 4; ++j) addrow(a[j]);
        }
        for (; e < s1; ++e) addrow(stage[e]);

        float s = rsqrtf((float)hist[dl] + 1.0f);      // dinv[d] from local hist
        float* op = out + (long)d * 128 + c;
        float4 r0 = make_float4(acc[0] * s + b0.x, acc[1] * s + b0.y,
                                acc[2] * s + b0.z, acc[3] * s + b0.w);
        float4 r1 = make_float4(acc[4] * s + b1.x, acc[5] * s + b1.y,
                                acc[6] * s + b1.z, acc[7] * s + b1.w);
        *(float4*)op = r0;
        *(float4*)(op + 4) = r1;
    }
}

// ============ launch ============

extern "C" void kernel_launch(void* const* d_in, const int* in_sizes, int n_in,
                              void* d_out, int out_size, void* d_ws, size_t ws_size,
                              hipStream_t stream) {
    const float* x  = (const float*)d_in[0];
    const int*   ei = (const int*)d_in[1];
    // d_in[2] = edge_attr (unused; GCN edge weight = 1)
    const float* W  = (const float*)d_in[3];
    const float* b  = (const float*)d_in[4];
    float* out = (float*)d_out;

    const int N = in_sizes[0] / 128;
    const int E = in_sizes[1] / 2;
    const int* src = ei;
    const int* dst = ei + E;
    const int NBUK = (N + 31) >> BSH;  // 3125 buckets for N=100000 (<= MAXBUK)

    // ---- workspace carve (~39 MB) ----
    char* p = (char*)d_ws;
    auto carve = [&](size_t bytes) { char* q = p; p += (bytes + 255) & ~(size_t)255; return q; };
    int*            bcur   = (int*)           carve((size_t)MAXBUK * 4);
    float*          dinv   = (float*)         carve((size_t)N * 4);
    unsigned*       packed = (unsigned*)      carve((size_t)MAXBUK * BCAP * 4);
    unsigned short* g      = (unsigned short*)carve((size_t)N * 128 * 2);

    const int gemmBlocks = (N + 63) / 64;

    hipMemsetAsync(bcur, 0, (size_t)NBUK * 4, stream);   // 12.5 KB

    k_scatgemm<<<NSCAT + gemmBlocks, TPB, 0, stream>>>(src, dst, bcur, packed,
                                                       x, W, g, N, E, NBUK);
    k_dinv    <<<NBUK, TPB, 0, stream>>>(packed, bcur, dinv, N);
    k_aggsort <<<NBUK, TPB, 0, stream>>>(packed, bcur, dinv, g, b, out, N);
}

// Round 15
// 228.630 us; speedup vs baseline: 1.0234x; 1.0234x over previous
//
#include <hip/hip_runtime.h>

#define TPB 256
#define NSCAT 512         // scatter blocks inside the fused kernel (R13-proven)
#define BSH 5             // node >> 5 -> bucket; 32 dsts per bucket
#define BCAP 1024         // fixed packed-region size per bucket (mean 512, +22sigma)
#define MAXBUK 3200       // LDS sizing cap for bucket arrays (N <= 102400)

typedef __attribute__((ext_vector_type(4))) float f32x4;
typedef __attribute__((ext_vector_type(8))) short short8;

__device__ __forceinline__ unsigned short f2bf(float f) {
    unsigned u = __float_as_uint(f);
    u = (u + 0x7fffu + ((u >> 16) & 1u)) >> 16;
    return (unsigned short)u;
}
__device__ __forceinline__ float bflo(unsigned u) { return __uint_as_float(u << 16); }
__device__ __forceinline__ float bfhi(unsigned u) { return __uint_as_float(u & 0xffff0000u); }

// ============ pass 1 (fused): bucket scatter (blocks 0..NSCAT-1) || gemm ========
// Scatter: LDS hist -> in-place cursor conversion (one returning base-grab per
// (block,bucket) with count>0) -> LDS-cursor scatter into fixed per-bucket
// regions. No per-edge global atomics (R8/R10: ~25ns each, any flavor).
// Gemm: g[i][j] = bf16( sum_k x[i][k]*W[j][k] ), UNSCALED; W staged in two
// 64-row half-tiles (17.4 KB LDS), x fragments preloaded to registers.

__global__ __launch_bounds__(256) void k_scatgemm(
    const int* __restrict__ src, const int* __restrict__ dst,
    int* __restrict__ bcur, unsigned* __restrict__ packed,
    const float* __restrict__ x, const float* __restrict__ W,
    unsigned short* __restrict__ g, int N, int E, int NBUK)
{
    __shared__ __align__(16) char smem[17408];
    const int t = threadIdx.x;

    if (blockIdx.x < NSCAT) {
        // ---------------- scatter half ----------------
        int* a = (int*)smem;                       // NBUK ints = 12.5 KB
        for (int i = t; i < NBUK; i += 256) a[i] = 0;
        __syncthreads();
        const int chunk = (E + NSCAT - 1) / NSCAT;
        const int lo = blockIdx.x * chunk;
        const int hi = min(E, lo + chunk);
        for (int e = lo + t; e < hi; e += 256)
            atomicAdd(&a[dst[e] >> BSH], 1);       // LDS atomic (hist)
        __syncthreads();
        for (int i = t; i < NBUK; i += 256) {
            int c = a[i];                          // count -> absolute cursor
            a[i] = i * BCAP + (c ? atomicAdd(&bcur[i], c) : 0);  // base grab
        }
        __syncthreads();
        for (int e = lo + t; e < hi; e += 256) {
            int d = dst[e];
            int bkt = d >> BSH;
            int pos = atomicAdd(&a[bkt], 1);       // LDS atomic
            if (pos < bkt * BCAP + BCAP)           // overflow guard (never here)
                packed[pos] = ((unsigned)src[e] << 8) | (unsigned)(d & 31);
        }
    } else {
        // ---------------- gemm half: 2x 64-row W half-tiles ----------------
        typedef unsigned short wb_t[136];
        wb_t* wb = (wb_t*)smem;                    // [64][136] bf16 = 17408 B

        const int lane = t & 63;
        const int wid  = t >> 6;
        const int l15  = lane & 15;
        const int quad = lane >> 4;
        const int row  = (blockIdx.x - NSCAT) * 64 + wid * 16 + l15;
        const int rowc = (row < N) ? row : (N - 1);

        // preload + convert all 4 x fragments (ks-dependent only; ~16 VGPR)
        short8 af[4];
        #pragma unroll
        for (int ks = 0; ks < 4; ++ks) {
            const int kb = ks * 32 + quad * 8;
            float4 a0 = *(const float4*)(x + (long)rowc * 128 + kb);
            float4 a1 = *(const float4*)(x + (long)rowc * 128 + kb + 4);
            union { unsigned short u[8]; short8 v; } cf;
            cf.u[0] = f2bf(a0.x); cf.u[1] = f2bf(a0.y); cf.u[2] = f2bf(a0.z); cf.u[3] = f2bf(a0.w);
            cf.u[4] = f2bf(a1.x); cf.u[5] = f2bf(a1.y); cf.u[6] = f2bf(a1.z); cf.u[7] = f2bf(a1.w);
            af[ks] = cf.v;
        }

        f32x4 acc[8];
        #pragma unroll
        for (int u = 0; u < 8; ++u) acc[u] = (f32x4){0.f, 0.f, 0.f, 0.f};

        #pragma unroll
        for (int half = 0; half < 2; ++half) {
            for (int ch = t; ch < 1024; ch += 256) {       // stage 64 W rows
                int nrow = ch >> 4, k8 = (ch & 15) << 3;
                const float* wp = W + (half * 64 + nrow) * 128 + k8;
                float4 w0 = *(const float4*)wp;
                float4 w1 = *(const float4*)(wp + 4);
                union { unsigned short u[8]; uint4 q; } pk;
                pk.u[0] = f2bf(w0.x); pk.u[1] = f2bf(w0.y); pk.u[2] = f2bf(w0.z); pk.u[3] = f2bf(w0.w);
                pk.u[4] = f2bf(w1.x); pk.u[5] = f2bf(w1.y); pk.u[6] = f2bf(w1.z); pk.u[7] = f2bf(w1.w);
                *(uint4*)&wb[nrow][k8] = pk.q;
            }
            __syncthreads();
            #pragma unroll
            for (int ks = 0; ks < 4; ++ks) {
                const int kb = ks * 32 + quad * 8;
                #pragma unroll
                for (int u = 0; u < 4; ++u) {
                    short8 bf = *(const short8*)&wb[u * 16 + l15][kb];
                    // swapped: W frag as A, x frag as B  ->  D[j][i]
                    acc[half * 4 + u] =
                        __builtin_amdgcn_mfma_f32_16x16x32_bf16(bf, af[ks], acc[half * 4 + u], 0, 0, 0);
                }
            }
            __syncthreads();                       // before next half overwrites wb
        }

        if (row < N) {
            unsigned short* gp = g + (long)row * 128 + quad * 4;
            #pragma unroll
            for (int u = 0; u < 8; ++u) {
                unsigned short u0 = f2bf(acc[u][0]);
                unsigned short u1 = f2bf(acc[u][1]);
                unsigned short u2 = f2bf(acc[u][2]);
                unsigned short u3 = f2bf(acc[u][3]);
                uint2 pk;
                pk.x = (unsigned)u0 | ((unsigned)u1 << 16);
                pk.y = (unsigned)u2 | ((unsigned)u3 << 16);
                *(uint2*)(gp + u * 16) = pk;       // 4 consecutive bf16 cols
            }
        }
    }
}

// ============ pass 2: per-bucket degree -> dinv (tiny: 12.8 MB read, 400 KB write) =

__global__ __launch_bounds__(256) void k_dinv(const unsigned* __restrict__ packed,
                                              const int* __restrict__ bcur,
                                              float* __restrict__ dinv, int N) {
    __shared__ int hist[32];
    const int b = blockIdx.x;
    const int t = threadIdx.x;
    if (t < 32) hist[t] = 0;
    __syncthreads();
    const int cnt = min(bcur[b], BCAP);
    const int base = b * BCAP;
    for (int e = t; e < cnt; e += 256)
        atomicAdd(&hist[packed[base + e] & 31u], 1);   // LDS atomic
    __syncthreads();
    if (t < 32) {
        int d = (b << BSH) + t;
        if (d < N) dinv[d] = rsqrtf((float)hist[t] + 1.0f);
    }
}

// ============ pass 3: fused LDS sort + aggregate, one 32-dst bucket per block ====
// R11/R13-proven (the measured optimum): hist -> shuffle scan -> LDS counting
// sort -> 32-lane/uint2 gather ladder with dinv[s] fma.
// out[d] = dinv[d]*( dinv[d]*g[d] + sum dinv[s]*g[s] ) + b.
// 32 lanes/dst is the empirically optimal gather shape (16-lane/uint4 regressed
// in both R2 and R14 — the kernel is latency/TLP-bound, not issue-count-bound).

__global__ __launch_bounds__(256) void k_aggsort(const unsigned* __restrict__ packed,
                                                 const int* __restrict__ bcur,
                                                 const float* __restrict__ dinv,
                                                 const unsigned short* __restrict__ g,
                                                 const float* __restrict__ b_,
                                                 float* __restrict__ out, int N) {
    __shared__ int hist[32], lbase[32], scur[32];
    __shared__ unsigned stage[BCAP];
    const int b = blockIdx.x;
    const int t = threadIdx.x;
    if (t < 32) hist[t] = 0;
    __syncthreads();
    const int cnt = min(bcur[b], BCAP);
    const int base = b * BCAP;
    for (int e = t; e < cnt; e += 256)
        atomicAdd(&hist[packed[base + e] & 31u], 1);   // LDS atomic
    __syncthreads();
    if (t < 32) {                                      // lanes 0..31 of wave 0
        int v = hist[t];
        int incl = v;
        #pragma unroll
        for (int d = 1; d < 32; d <<= 1) {
            int o = __shfl_up(incl, d);
            if (t >= d) incl += o;
        }
        lbase[t] = incl - v;
        scur[t]  = incl - v;
    }
    __syncthreads();
    for (int e = t; e < cnt; e += 256) {
        unsigned pk = packed[base + e];
        int pos = atomicAdd(&scur[pk & 31u], 1);       // LDS atomic
        stage[pos] = pk & 0xffffff00u;                 // byte offset (src*256)
    }
    __syncthreads();

    // aggregate: 8 dsts per round (32 lanes each), 4 rounds
    const int c = (t & 31) << 2;
    const char* gb = (const char*)g + (c << 1);        // lane base in a g-row
    #pragma unroll 1
    for (int round = 0; round < 4; ++round) {
        const int dl = round * 8 + (t >> 5);
        const int d  = (b << BSH) + dl;
        if (d >= N) continue;

        float4 acc = make_float4(0.f, 0.f, 0.f, 0.f);
        auto addrow = [&](unsigned off) {              // off = byte offset of g-row
            float dv = dinv[off >> 8];
            uint2 p = *(const uint2*)(gb + off);
            acc.x = fmaf(bflo(p.x), dv, acc.x);
            acc.y = fmaf(bfhi(p.x), dv, acc.y);
            acc.z = fmaf(bflo(p.y), dv, acc.z);
            acc.w = fmaf(bfhi(p.y), dv, acc.w);
        };

        addrow((unsigned)d << 8);                      // self-loop: dinv[d]*g[d]
        int e  = lbase[dl];
        int s1 = e + hist[dl];
        for (; e + 8 <= s1; e += 8) {
            unsigned a[8];
            #pragma unroll
            for (int j = 0; j < 8; ++j) a[j] = stage[e + j];
            #pragma unroll
            for (int j = 0; j < 8; ++j) addrow(a[j]);
        }
        for (; e + 4 <= s1; e += 4) {
            unsigned a[4];
            #pragma unroll
            for (int j = 0; j < 4; ++j) a[j] = stage[e + j];
            #pragma unroll
            for (int j = 0; j < 4; ++j) addrow(a[j]);
        }
        for (; e < s1; ++e) addrow(stage[e]);

        float s = rsqrtf((float)hist[dl] + 1.0f);      // dinv[d] from local hist
        float4 bb = *(const float4*)(b_ + c);
        float4 r = make_float4(acc.x * s + bb.x, acc.y * s + bb.y,
                               acc.z * s + bb.z, acc.w * s + bb.w);
        *(float4*)(out + (long)d * 128 + c) = r;
    }
}

// ============ launch ============

extern "C" void kernel_launch(void* const* d_in, const int* in_sizes, int n_in,
                              void* d_out, int out_size, void* d_ws, size_t ws_size,
                              hipStream_t stream) {
    const float* x  = (const float*)d_in[0];
    const int*   ei = (const int*)d_in[1];
    // d_in[2] = edge_attr (unused; GCN edge weight = 1)
    const float* W  = (const float*)d_in[3];
    const float* b  = (const float*)d_in[4];
    float* out = (float*)d_out;

    const int N = in_sizes[0] / 128;
    const int E = in_sizes[1] / 2;
    const int* src = ei;
    const int* dst = ei + E;
    const int NBUK = (N + 31) >> BSH;  // 3125 buckets for N=100000 (<= MAXBUK)

    // ---- workspace carve (~39 MB) ----
    char* p = (char*)d_ws;
    auto carve = [&](size_t bytes) { char* q = p; p += (bytes + 255) & ~(size_t)255; return q; };
    int*            bcur   = (int*)           carve((size_t)MAXBUK * 4);
    float*          dinv   = (float*)         carve((size_t)N * 4);
    unsigned*       packed = (unsigned*)      carve((size_t)MAXBUK * BCAP * 4);
    unsigned short* g      = (unsigned short*)carve((size_t)N * 128 * 2);

    const int gemmBlocks = (N + 63) / 64;

    hipMemsetAsync(bcur, 0, (size_t)NBUK * 4, stream);   // 12.5 KB

    k_scatgemm<<<NSCAT + gemmBlocks, TPB, 0, stream>>>(src, dst, bcur, packed,
                                                       x, W, g, N, E, NBUK);
    k_dinv    <<<NBUK, TPB, 0, stream>>>(packed, bcur, dinv, N);
    k_aggsort <<<NBUK, TPB, 0, stream>>>(packed, bcur, dinv, g, b, out, N);
}